// Round 9
// baseline (173.632 us; speedup 1.0000x reference)
//
#include <hip/hip_runtime.h>
#include <hip/hip_bf16.h>
#include <math.h>

#define HSZ   1024
#define NHEAD 16
#define HDIM  64
#define BATCH 2
#define SEQ   2048

#define LOG2E 1.4426950408889634f

typedef __attribute__((ext_vector_type(8))) short short8;
typedef __attribute__((ext_vector_type(4))) short short4_t;
typedef __attribute__((ext_vector_type(4))) float floatx4;

typedef __attribute__((address_space(1))) const unsigned int gu32;
typedef __attribute__((address_space(3))) unsigned int lu32;

__device__ __forceinline__ void g2lds16(const void* g, void* l) {
    // async global->LDS DMA, 16B per lane; LDS dest = wave-uniform base + lane*16
    __builtin_amdgcn_global_load_lds((gu32*)g, (lu32*)l, 16, 0, 0);
}

__device__ __forceinline__ short f2bf(float f) {
    union { float f; unsigned u; } v; v.f = f;
    unsigned r = (v.u + 0x7FFF + ((v.u >> 16) & 1)) >> 16;  // RNE
    return (short)r;
}

__device__ __forceinline__ unsigned pk2(float a, float b) {
    __hip_bfloat162 h = __float22bfloat162_rn(make_float2(a, b));
    return *(unsigned*)&h;   // low = a, high = b
}

__device__ __forceinline__ float ex2(float x) {
#if __has_builtin(__builtin_amdgcn_exp2f)
    return __builtin_amdgcn_exp2f(x);
#else
    return exp2f(x);
#endif
}

// PV uses K=16 MFMA (P-fragment is an identity repack of the S^T C-layout)
#if __has_builtin(__builtin_amdgcn_mfma_f32_16x16x16_bf16)
#define MFMA16(a, b, c) __builtin_amdgcn_mfma_f32_16x16x16_bf16(a, b, c, 0, 0, 0)
#else
#define MFMA16(a, b, c) __builtin_amdgcn_mfma_f32_16x16x16bf16_1k(a, b, c, 0, 0, 0)
#endif

// ---------------------------------------------------------------------------
// K1: fp32 -> bf16 convert (X, Wq|Wk|Wv concat) + mask prescale by log2e
// ---------------------------------------------------------------------------
__global__ __launch_bounds__(256) void convert_kernel(
    const float4* __restrict__ X, const float4* __restrict__ Wq,
    const float4* __restrict__ Wk, const float4* __restrict__ Wv,
    const float4* __restrict__ Mask,
    short4_t* __restrict__ Xb, short4_t* __restrict__ Wb,
    float4* __restrict__ Mw)
{
    int idx = blockIdx.x * 256 + threadIdx.x;      // 1,836,032 total
    if (idx >= 1835008) {                           // mask: 1024 float4
        int t = idx - 1835008;
        float4 f = Mask[t];
        float4 o;
        o.x = f.x * LOG2E; o.y = f.y * LOG2E;
        o.z = f.z * LOG2E; o.w = f.w * LOG2E;
        Mw[t] = o;
        return;
    }
    const float4* src; short4_t* dst;
    if (idx < 1048576) { src = X + idx; dst = Xb + idx; }
    else {
        int t = idx - 1048576;
        int sel = t >> 18;                          // 262144 float4 per W
        int wi  = t & 0x3FFFF;
        src = (sel == 0 ? Wq : sel == 1 ? Wk : Wv) + wi;
        dst = Wb + (sel << 18) + wi;
    }
    float4 f = *src;
    short4_t o;
    o.x = f2bf(f.x); o.y = f2bf(f.y); o.z = f2bf(f.z); o.w = f2bf(f.w);
    *dst = o;
}

// ---------------------------------------------------------------------------
// K2: QKV projection, bf16 MFMA. C[4096][3072] = Xb[4096][1024] * Wb^T.
// 128x128 tile, BK=64, global_load_lds w=16, XOR-swizzled LDS.
// q -> [B,NH,S,HD] scaled by 0.125*log2e; k -> [B,NH,S,HD];
// v -> TRANSPOSED [B*NH, HD, S] (no key permutation: PV uses K=16 MFMA and
//     the S^T C-layout -> A-frag mapping is identity).
// ---------------------------------------------------------------------------
__global__ __launch_bounds__(256, 3) void qkv_mfma_kernel(
    const short* __restrict__ Xb, const short* __restrict__ Wb,
    const float* __restrict__ bq, const float* __restrict__ bk,
    const float* __restrict__ bv,
    short* __restrict__ qo, short* __restrict__ ko, short* __restrict__ vT)
{
    __shared__ short Sm[128 * 136];      // A/B staging (16384) + epilogue buffer
    short* As = Sm;
    short* Bs = Sm + 8192;

    const int tid  = threadIdx.x;
    const int lane = tid & 63;
    const int w    = tid >> 6;
    const int l    = lane & 15, quad = lane >> 4;
    const int gM   = blockIdx.y * 128;
    const int gN   = blockIdx.x * 128;      // 0..3071 across q|k|v
    const int wm   = (w >> 1) * 64, wn = (w & 1) * 64;
    const int ci   = lane >> 3, pb = lane & 7;

    floatx4 acc[4][4] = {};

    for (int kt = 0; kt < HSZ / 64; ++kt) {
        const int k0 = kt * 64;
        __syncthreads();
        #pragma unroll
        for (int u = 0; u < 4; ++u) {
            int c  = w * 4 + u;                 // chunk 0..15 (1KB each)
            int r  = c * 8 + ci;                // tile row
            int lb = pb ^ (r & 7);              // logical 16B block
            g2lds16(Xb + (size_t)(gM + r) * HSZ + k0 + lb * 8, &As[c * 512]);
            g2lds16(Wb + (size_t)(gN + r) * HSZ + k0 + lb * 8, &Bs[c * 512]);
        }
        __syncthreads();
        #pragma unroll
        for (int kk = 0; kk < 2; ++kk) {
            short8 a[4], b[4];
            #pragma unroll
            for (int i = 0; i < 4; ++i) {
                int m = wm + i * 16 + l;
                a[i] = *(const short8*)&As[m * 64 + (((quad + kk * 4) ^ (m & 7)) << 3)];
                int n = wn + i * 16 + l;
                b[i] = *(const short8*)&Bs[n * 64 + (((quad + kk * 4) ^ (n & 7)) << 3)];
            }
            #pragma unroll
            for (int i = 0; i < 4; ++i)
                #pragma unroll
                for (int j = 0; j < 4; ++j)
                    acc[i][j] = __builtin_amdgcn_mfma_f32_16x16x32_bf16(
                        a[i], b[j], acc[i][j], 0, 0, 0);
        }
    }

    const int mat = gN >> 10;                   // 0=q 1=k 2=v
    const int bb = gM >> 11, ss0 = gM & (SEQ - 1);

    if (mat == 2) {
        // V: bias + LDS transpose, write [bh][d][s] (identity key order)
        __syncthreads();
        #pragma unroll
        for (int j = 0; j < 4; ++j) {
            int fl = wn + j * 16 + l;               // feature local 0..127
            float bv_ = bv[(gN & 1023) + fl];
            #pragma unroll
            for (int i = 0; i < 4; ++i)
                #pragma unroll
                for (int r = 0; r < 4; ++r)
                    Sm[fl * 136 + wm + i * 16 + quad * 4 + r]
                        = f2bf(acc[i][j][r] + bv_);
        }
        __syncthreads();
        #pragma unroll
        for (int it = 0; it < 16; ++it) {
            int f = (tid >> 5) + it * 8;
            int c = (tid & 31) * 4;
            short4_t val = *(const short4_t*)&Sm[f * 136 + c];
            int nft = (gN & 1023) + f;
            int head = nft >> 6, d = nft & 63;
            *(short4_t*)&vT[(((size_t)(bb * NHEAD + head)) * HDIM + d) * SEQ
                            + ss0 + c] = val;
        }
        return;
    }

    // Q/K: bias+scale into Sm [row][feat], then coalesced short8 stores
    const float* bias = (mat == 0) ? bq : bk;
    short* dst        = (mat == 0) ? qo : ko;
    const float qscale = (mat == 0) ? 0.125f * LOG2E : 1.0f;

    __syncthreads();
    #pragma unroll
    for (int j = 0; j < 4; ++j) {
        int fl = wn + j * 16 + l;                   // feature local 0..127
        float bb_ = bias[(gN & 1023) + fl];
        #pragma unroll
        for (int i = 0; i < 4; ++i)
            #pragma unroll
            for (int r = 0; r < 4; ++r)
                Sm[(wm + i * 16 + quad * 4 + r) * 136 + fl]
                    = f2bf((acc[i][j][r] + bb_) * qscale);
    }
    __syncthreads();
    #pragma unroll
    for (int it = 0; it < 8; ++it) {
        int row = (tid >> 4) + it * 16;             // 0..127 (s-local)
        int fc  = (tid & 15) * 8;                   // feature 0..120
        short8 val = *(const short8*)&Sm[row * 136 + fc];
        int nft = (gN & 1023) + fc;
        int head = nft >> 6, d = nft & 63;
        *(short8*)&dst[(((size_t)(bb * NHEAD + head)) * SEQ + ss0 + row) * HDIM + d]
            = val;
    }
}

// ---------------------------------------------------------------------------
// K3: MFMA flash attention, kh-quarter split + cross-iteration pipeline.
//   Grid 1024 = 32 qt x 32 bh (idx&31=bh -> XCD-affine L2). Q-tile 64.
//   Wave kh=w owns ALL 64 queries x 16 keys (quarter) of each 64-key tile:
//     - K-frags unique per wave (2x ds_read_b128/iter)
//     - V-frags are b64 reads (4x/iter)  -> DS halved vs qh/kh half-split
//   S^T = K Q^T (16x16x32) + mask-as-acc-init; no-max exp2 softmax.
//   PV  = 16x16x16 MFMA, K=16 contraction: P A-frag is an IDENTITY register
//   repack of the S^T C-layout (key slot quad*4+j == C row quad*4+r).
//   PIPELINE: S_t computed in iter t-1 tail; body = exp/pack(S_t) + PV on
//   registers only, then barrier, then frag-reads + S_{t+1} -> each barrier
//   phase mixes VALU+MFMA+DS instead of serial S->exp->PV.
//   4-way kh partial O/l combined via LDS tree at the end (shift-free
//   softmax => additive partials). LDS 33 KB; VGPR ~160 -> 3 blocks/CU.
// ---------------------------------------------------------------------------
__global__ __launch_bounds__(256, 3) void attn_kernel(
    const short* __restrict__ Qg, const short* __restrict__ Kg,
    const short* __restrict__ VTg, const float* __restrict__ maskw,
    float* __restrict__ out)
{
    __shared__ alignas(16) short Sh[4][4096];   // buf b: K=Sh[2b], V=Sh[2b+1]
    __shared__ alignas(16) float Ms[2][64];
    __shared__ alignas(16) float Lx[4][4][16];

    const int tid  = threadIdx.x;
    const int lane = tid & 63;
    const int kh   = tid >> 6;              // wave = key quarter
    const int l    = lane & 15, quad = lane >> 4;
    const int idx  = blockIdx.x;
    const int bh   = idx & 31;              // bh%8 == XCD -> K/V stays in one L2
    const int qt   = idx >> 5;              // 32 Q-tiles of 64
    const int batch = bh >> 4, head = bh & 15;
    const int ci = lane >> 3, pb = lane & 7;

    const short* Qb = Qg + ((size_t)bh * SEQ + qt * 64) * HDIM;
    const short* Kb = Kg + (size_t)bh * SEQ * HDIM;
    const short* Vb = VTg + (size_t)bh * HDIM * SEQ;
    const float* mrow = maskw + (size_t)batch * SEQ;   // pre-scaled by log2e

    short* Qst = (short*)&Sh[2][0];        // 8 KB Q staging overlay (Sh[2])

    // stage Q into overlay; K/V tile 0 into buffer 0; mask 0
    #pragma unroll
    for (int u = 0; u < 2; ++u) {
        int c = kh * 2 + u;
        int r = c * 8 + ci;
        int lb = pb ^ (r & 7);
        g2lds16(Qb + (size_t)r * HDIM + lb * 8, &Qst[c * 512]);
        g2lds16(Kb + (size_t)r * HDIM + lb * 8, &Sh[0][c * 512]);
        g2lds16(Vb + (size_t)r * SEQ + lb * 8, &Sh[1][c * 512]);
    }
    if (tid < 16) g2lds16(mrow + tid * 4, &Ms[0][0]);
    __syncthreads();

    // hoist Q B-fragments (queries m = n*16 + l, all 64)
    short8 aq[4][2];
    #pragma unroll
    for (int n = 0; n < 4; ++n)
        #pragma unroll
        for (int kk = 0; kk < 2; ++kk) {
            int m = n * 16 + l;
            aq[n][kk] = *(const short8*)&Qst[m * 64
                          + (((quad + kk * 4) ^ (m & 7)) << 3)];
        }
    __syncthreads();   // all waves done reading Q before DMA overwrites

    // issue DMA tile 1 -> buffer 1 (overlay region now free)
    #pragma unroll
    for (int u = 0; u < 2; ++u) {
        int c = kh * 2 + u;
        int r = c * 8 + ci;
        int lb = pb ^ (r & 7);
        g2lds16(Kb + (size_t)(64 + r) * HDIM + lb * 8, &Sh[2][c * 512]);
        g2lds16(Vb + (size_t)r * SEQ + 64 + lb * 8, &Sh[3][c * 512]);
    }
    if (tid < 16) g2lds16(mrow + 64 + tid * 4, &Ms[1][0]);

    // frag-read helpers (addresses constant per wave except buffer base)
    const int akoff0 = (kh * 16 + l) * 64 + (((quad + 0) ^ ((kh * 16 + l) & 7)) << 3);
    const int akoff1 = (kh * 16 + l) * 64 + (((quad + 4) ^ ((kh * 16 + l) & 7)) << 3);
    const int blog   = kh * 2 + (quad >> 1);    // V 16B-block index
    const int bhalf  = (quad & 1) * 4;          // 8B half within block

    // read tile-0 fragments + compute S_0
    short8 ak0 = *(const short8*)&Sh[0][akoff0];
    short8 ak1 = *(const short8*)&Sh[0][akoff1];
    short4_t bvf[4];
    #pragma unroll
    for (int nd = 0; nd < 4; ++nd) {
        int d = nd * 16 + l;
        bvf[nd] = *(const short4_t*)&Sh[1][d * 64 + ((blog ^ (d & 7)) << 3) + bhalf];
    }
    floatx4 s[4];
    {
        float4 mq = *(const float4*)&Ms[0][kh * 16 + quad * 4];
        floatx4 ini = {mq.x, mq.y, mq.z, mq.w};
        #pragma unroll
        for (int n = 0; n < 4; ++n) s[n] = ini;
        #pragma unroll
        for (int n = 0; n < 4; ++n) {
            s[n] = __builtin_amdgcn_mfma_f32_16x16x32_bf16(ak0, aq[n][0], s[n], 0, 0, 0);
            s[n] = __builtin_amdgcn_mfma_f32_16x16x32_bf16(ak1, aq[n][1], s[n], 0, 0, 0);
        }
    }

    floatx4 o[4][4] = {};
    float l_i[4] = {0.f, 0.f, 0.f, 0.f};

    for (int t = 0; t < 32; ++t) {
        // ---- body: registers only -- exp/pack P_t, PV with V_t frags ----
        short4_t ap[4];
        #pragma unroll
        for (int n = 0; n < 4; ++n) {
            s[n][0] = ex2(s[n][0]);
            s[n][1] = ex2(s[n][1]);
            s[n][2] = ex2(s[n][2]);
            s[n][3] = ex2(s[n][3]);
            l_i[n] += (s[n][0] + s[n][1]) + (s[n][2] + s[n][3]);
            union { unsigned u[2]; short4_t s4; } pu;
            pu.u[0] = pk2(s[n][0], s[n][1]);
            pu.u[1] = pk2(s[n][2], s[n][3]);
            ap[n] = pu.s4;
        }
        #pragma unroll
        for (int nq = 0; nq < 4; ++nq)
            #pragma unroll
            for (int nd = 0; nd < 4; ++nd)
                o[nq][nd] = MFMA16(ap[nq], bvf[nd], o[nq][nd]);

        // ---- tail: next tile's fragments + S_{t+1} ----
        if (t < 31) {
            __syncthreads();               // tile t+1 DMA complete; buf[t&1] free
            if (t < 30) {                  // DMA tile t+2 -> buf[t&1]
                const int r0 = (t + 2) * 64;
                const int bd = t & 1;
                #pragma unroll
                for (int u = 0; u < 2; ++u) {
                    int c = kh * 2 + u;
                    int r = c * 8 + ci;
                    int lb = pb ^ (r & 7);
                    g2lds16(Kb + (size_t)(r0 + r) * HDIM + lb * 8,
                            &Sh[2 * bd][c * 512]);
                    g2lds16(Vb + (size_t)r * SEQ + r0 + lb * 8,
                            &Sh[2 * bd + 1][c * 512]);
                }
                if (tid < 16) g2lds16(mrow + r0 + tid * 4, &Ms[t & 1][0]);
            }
            const int bb = (t + 1) & 1;
            ak0 = *(const short8*)&Sh[2 * bb][akoff0];
            ak1 = *(const short8*)&Sh[2 * bb][akoff1];
            #pragma unroll
            for (int nd = 0; nd < 4; ++nd) {
                int d = nd * 16 + l;
                bvf[nd] = *(const short4_t*)&Sh[2 * bb + 1]
                              [d * 64 + ((blog ^ (d & 7)) << 3) + bhalf];
            }
            float4 mq = *(const float4*)&Ms[bb][kh * 16 + quad * 4];
            floatx4 ini = {mq.x, mq.y, mq.z, mq.w};
            #pragma unroll
            for (int n = 0; n < 4; ++n) s[n] = ini;
            #pragma unroll
            for (int n = 0; n < 4; ++n) {
                s[n] = __builtin_amdgcn_mfma_f32_16x16x32_bf16(ak0, aq[n][0], s[n], 0, 0, 0);
                s[n] = __builtin_amdgcn_mfma_f32_16x16x32_bf16(ak1, aq[n][1], s[n], 0, 0, 0);
            }
        }
    }

    // ---- 4-way kh combine (shift-free softmax => partials additive) ----
    // quad-reduce l first (quads hold different keys of the same query)
    #pragma unroll
    for (int n = 0; n < 4; ++n) {
        float v = l_i[n];
        v += __shfl_xor(v, 16);
        v += __shfl_xor(v, 32);
        l_i[n] = v;
    }
    float* r0buf = (float*)&Sh[0][0];   // 16 KB (Sh[0..1])
    float* r1buf = (float*)&Sh[2][0];   // 16 KB (Sh[2..3])
    __syncthreads();                    // all tail LDS reads complete
    if (kh != 0 && lane < 16) {
        #pragma unroll
        for (int n = 0; n < 4; ++n) Lx[kh][n][lane] = l_i[n];
    }
    if (kh == 1 || kh == 3) {
        float* dstb = (kh == 1) ? r0buf : r1buf;
        #pragma unroll
        for (int nq = 0; nq < 4; ++nq)
            #pragma unroll
            for (int nd = 0; nd < 4; ++nd)
                *(floatx4*)&dstb[((nq * 4 + nd) * 64 + lane) * 4] = o[nq][nd];
    }
    __syncthreads();
    if (kh == 0 || kh == 2) {
        const float* srcb = (kh == 0) ? r0buf : r1buf;
        #pragma unroll
        for (int nq = 0; nq < 4; ++nq)
            #pragma unroll
            for (int nd = 0; nd < 4; ++nd)
                o[nq][nd] += *(const floatx4*)&srcb[((nq * 4 + nd) * 64 + lane) * 4];
    }
    __syncthreads();
    if (kh == 2) {
        #pragma unroll
        for (int nq = 0; nq < 4; ++nq)
            #pragma unroll
            for (int nd = 0; nd < 4; ++nd)
                *(floatx4*)&r0buf[((nq * 4 + nd) * 64 + lane) * 4] = o[nq][nd];
    }
    __syncthreads();
    if (kh == 0) {
        #pragma unroll
        for (int nq = 0; nq < 4; ++nq)
            #pragma unroll
            for (int nd = 0; nd < 4; ++nd)
                o[nq][nd] += *(const floatx4*)&r0buf[((nq * 4 + nd) * 64 + lane) * 4];
        float lf[4];
        #pragma unroll
        for (int n = 0; n < 4; ++n)
            lf[n] = l_i[n] + Lx[1][n][l] + Lx[2][n][l] + Lx[3][n][l];
        // epilogue: out[b][s][h*64+d]; query = nq*16+quad*4+r, d = nd*16+l
        #pragma unroll
        for (int nq = 0; nq < 4; ++nq) {
            #pragma unroll
            for (int r = 0; r < 4; ++r) {
                float inv = 1.0f / __shfl(lf[nq], (lane & 48) + quad * 4 + r);
                int qrow = qt * 64 + nq * 16 + quad * 4 + r;
                #pragma unroll
                for (int nd = 0; nd < 4; ++nd)
                    out[((size_t)batch * SEQ + qrow) * HSZ + head * HDIM + nd * 16 + l]
                        = o[nq][nd][r] * inv;
            }
        }
    }
}

extern "C" void kernel_launch(void* const* d_in, const int* in_sizes, int n_in,
                              void* d_out, int out_size, void* d_ws, size_t ws_size,
                              hipStream_t stream) {
    const float* hs   = (const float*)d_in[0];
    const float* mask = (const float*)d_in[1];
    const float* Wq   = (const float*)d_in[2];
    const float* bq   = (const float*)d_in[3];
    const float* Wk   = (const float*)d_in[4];
    const float* bk   = (const float*)d_in[5];
    const float* Wv   = (const float*)d_in[6];
    const float* bv   = (const float*)d_in[7];
    float* out = (float*)d_out;

    // ws (shorts): Xb 4.19M | Wb 3.15M | qb | kb | vT (4.19M each) | Mw fp32
    short* Xb = (short*)d_ws;
    short* Wb = Xb + 4194304;
    short* qb = Wb + 3145728;
    short* kb = qb + 4194304;
    short* vT = kb + 4194304;
    float* Mw = (float*)(vT + 4194304);   // 4096 floats

    convert_kernel<<<7172, 256, 0, stream>>>(
        (const float4*)hs, (const float4*)Wq, (const float4*)Wk, (const float4*)Wv,
        (const float4*)mask, (short4_t*)Xb, (short4_t*)Wb, (float4*)Mw);

    dim3 g2(3 * HSZ / 128, BATCH * SEQ / 128);   // 24 x 32
    qkv_mfma_kernel<<<g2, 256, 0, stream>>>(Xb, Wb, bq, bk, bv, qb, kb, vT);

    attn_kernel<<<1024, 256, 0, stream>>>(qb, kb, vT, Mw, out);
}